// Round 12
// baseline (224.238 us; speedup 1.0000x reference)
//
#include <hip/hip_runtime.h>

#define ST 512           // threads, scatter kernel
#define EPB 8192         // edges per scatter block
#define DT 512           // threads, degree/y kernel
#define FT 512           // threads, accumulate+node kernel
#define S_LOG 8
#define S 256            // nodes per bucket
#define CAP 8912         // records per bucket (mean 8192 + 8 sigma)
#define MAXB 512         // bucket-array bound == ST (one entry per thread!)

__device__ __forceinline__ void gAtomAdd(float* p, float v) {
    unsafeAtomicAdd(p, v);  // hardware global_atomic_add_f32
}

// Init bucket cursors to fixed bases + zero g.
__global__ void k_init(int* __restrict__ cur_d, int* __restrict__ cur_s,
                       float* __restrict__ g, int nb) {
    int t = threadIdx.x;
    if (t < nb) { cur_d[t] = t * CAP; cur_s[t] = t * CAP; }
    if (t < 64) g[t] = 0.0f;
}

// Fused double bucket-scatter, rank-first (1 LDS atomic per record per phase).
// rec[pos] = (pay << 8) | (key & 255), grouped by key>>8 at fixed bucket bases.
// MAXB == ST: every bucket-array op is exactly one entry per thread. (R10-proven)
__global__ void __launch_bounds__(ST) k_sctr2(
        const int4* __restrict__ src4, const int4* __restrict__ dst4, int E,
        int* __restrict__ cur_d, int* __restrict__ cur_s,
        unsigned* __restrict__ rec_d, unsigned* __restrict__ rec_s, int nb) {
    __shared__ unsigned lrec[EPB];          // 32 KB
    __shared__ unsigned short lbkt[EPB];    // 16 KB
    __shared__ int cnt[MAXB];
    __shared__ int lst[MAXB];
    __shared__ int gb[MAXB];
    int t = threadIdx.x;
    int E4 = E >> 2;
    int b4 = blockIdx.x * (EPB / 4);
    int m = min(EPB, E - blockIdx.x * EPB);

    int4 dk[4], sk[4];
    bool v[4];
    #pragma unroll
    for (int k = 0; k < 4; ++k) {
        int idx = b4 + k * ST + t;
        v[k] = idx < E4;
        if (v[k]) { dk[k] = dst4[idx]; sk[k] = src4[idx]; }
    }

    for (int ph = 0; ph < 2; ++ph) {        // 0: by dst (pay src); 1: by src (pay dst)
        int* cursor = ph ? cur_s : cur_d;
        unsigned* rec = ph ? rec_s : rec_d;
        cnt[t] = 0;
        __syncthreads();
        int rk[16];
        #pragma unroll
        for (int k = 0; k < 4; ++k) {
            if (v[k]) {
                int4 K = ph ? sk[k] : dk[k];
                rk[4 * k + 0] = atomicAdd(&cnt[K.x >> S_LOG], 1);
                rk[4 * k + 1] = atomicAdd(&cnt[K.y >> S_LOG], 1);
                rk[4 * k + 2] = atomicAdd(&cnt[K.z >> S_LOG], 1);
                rk[4 * k + 3] = atomicAdd(&cnt[K.w >> S_LOG], 1);
            }
        }
        __syncthreads();
        int c = cnt[t];
        for (int o = 1; o < MAXB; o <<= 1) {
            int u = (t >= o) ? cnt[t - o] : 0;
            __syncthreads();
            cnt[t] += u;
            __syncthreads();
        }
        lst[t] = cnt[t] - c;
        gb[t] = (c > 0) ? atomicAdd(&cursor[t], c) : 0;
        __syncthreads();
        #pragma unroll
        for (int k = 0; k < 4; ++k) {
            if (v[k]) {
                int4 K = ph ? sk[k] : dk[k];
                int4 P = ph ? dk[k] : sk[k];
                int bb, p;
                bb = K.x >> S_LOG; p = lst[bb] + rk[4 * k + 0];
                lrec[p] = ((unsigned)P.x << S_LOG) | (unsigned)(K.x & (S - 1));
                lbkt[p] = (unsigned short)bb;
                bb = K.y >> S_LOG; p = lst[bb] + rk[4 * k + 1];
                lrec[p] = ((unsigned)P.y << S_LOG) | (unsigned)(K.y & (S - 1));
                lbkt[p] = (unsigned short)bb;
                bb = K.z >> S_LOG; p = lst[bb] + rk[4 * k + 2];
                lrec[p] = ((unsigned)P.z << S_LOG) | (unsigned)(K.z & (S - 1));
                lbkt[p] = (unsigned short)bb;
                bb = K.w >> S_LOG; p = lst[bb] + rk[4 * k + 3];
                lrec[p] = ((unsigned)P.w << S_LOG) | (unsigned)(K.w & (S - 1));
                lbkt[p] = (unsigned short)bb;
            }
        }
        __syncthreads();
        for (int i = t; i < m; i += ST) {   // coalesced per-bucket-run flush
            int bb = lbkt[i];
            rec[gb[bb] + (i - lst[bb])] = lrec[i];
        }
        __syncthreads();
    }
}

// Per dst-bucket: in-degree histogram (1 LDS atomic/record) -> dinv + y = dinv*x.
// No sort, no writeback.
__global__ void __launch_bounds__(DT) k_dy(
        const unsigned* __restrict__ rec_d, const int* __restrict__ cur_d,
        const float4* __restrict__ x, float* __restrict__ dinv,
        float4* __restrict__ y, int n) {
    __shared__ int cnt[S];
    int b = blockIdx.x, t = threadIdx.x;
    int lo = b * CAP;
    int md = cur_d[b] - lo;
    if (t < S) cnt[t] = 0;
    __syncthreads();
    int m4 = md >> 2;
    const uint4* r4 = (const uint4*)(rec_d + lo);
    for (int i = t; i < m4; i += DT) {
        uint4 r = r4[i];
        atomicAdd(&cnt[r.x & (S - 1)], 1);
        atomicAdd(&cnt[r.y & (S - 1)], 1);
        atomicAdd(&cnt[r.z & (S - 1)], 1);
        atomicAdd(&cnt[r.w & (S - 1)], 1);
    }
    for (int i = (m4 << 2) + t; i < md; i += DT)
        atomicAdd(&cnt[rec_d[lo + i] & (S - 1)], 1);
    __syncthreads();
    if (t < S) {
        int nd = (b << S_LOG) + t;
        if (nd < n) {
            float dv = rsqrtf((float)cnt[t] + 1.0f);
            dinv[nd] = dv;
            float4 xi = x[nd];
            y[nd] = make_float4(dv * xi.x, dv * xi.y, dv * xi.z, dv * xi.w);
        }
    }
}

// Per bucket: SoA-LDS p1 accumulate (y-gathers from rec_d) + sumd (dinv-gathers
// from rec_s), then matvec + relu + weighted g-reduce. No node-level sort.
__global__ void __launch_bounds__(FT) k_acc2(
        const unsigned* __restrict__ rec_d, const unsigned* __restrict__ rec_s,
        const int* __restrict__ cur_d, const int* __restrict__ cur_s,
        const float4* __restrict__ y, const float* __restrict__ dinv,
        const float* __restrict__ W1, const float* __restrict__ b1,
        float* __restrict__ g, int n) {
    __shared__ float a0[S], a1[S], a2[S], a3[S], sd[S];  // SoA: bank = loc&31, ~2-way
    __shared__ float red[FT];
    int b = blockIdx.x, t = threadIdx.x;
    int lo = b * CAP;
    if (t < S) { a0[t] = 0.0f; a1[t] = 0.0f; a2[t] = 0.0f; a3[t] = 0.0f; sd[t] = 0.0f; }
    __syncthreads();
    {
        int md = cur_d[b] - lo;
        int m4 = md >> 2;
        const uint4* r4 = (const uint4*)(rec_d + lo);
        for (int i = t; i < m4; i += FT) {
            uint4 r = r4[i];
            float4 y0 = y[r.x >> S_LOG], y1 = y[r.y >> S_LOG];
            float4 y2 = y[r.z >> S_LOG], y3 = y[r.w >> S_LOG];
            int l0 = r.x & (S - 1), l1 = r.y & (S - 1);
            int l2 = r.z & (S - 1), l3 = r.w & (S - 1);
            atomicAdd(&a0[l0], y0.x); atomicAdd(&a1[l0], y0.y);
            atomicAdd(&a2[l0], y0.z); atomicAdd(&a3[l0], y0.w);
            atomicAdd(&a0[l1], y1.x); atomicAdd(&a1[l1], y1.y);
            atomicAdd(&a2[l1], y1.z); atomicAdd(&a3[l1], y1.w);
            atomicAdd(&a0[l2], y2.x); atomicAdd(&a1[l2], y2.y);
            atomicAdd(&a2[l2], y2.z); atomicAdd(&a3[l2], y2.w);
            atomicAdd(&a0[l3], y3.x); atomicAdd(&a1[l3], y3.y);
            atomicAdd(&a2[l3], y3.z); atomicAdd(&a3[l3], y3.w);
        }
        for (int i = (m4 << 2) + t; i < md; i += FT) {
            unsigned r = rec_d[lo + i];
            float4 ys = y[r >> S_LOG];
            int l = r & (S - 1);
            atomicAdd(&a0[l], ys.x); atomicAdd(&a1[l], ys.y);
            atomicAdd(&a2[l], ys.z); atomicAdd(&a3[l], ys.w);
        }
    }
    {
        int ms = cur_s[b] - lo;
        int m4 = ms >> 2;
        const uint4* r4 = (const uint4*)(rec_s + lo);
        for (int i = t; i < m4; i += FT) {
            uint4 r = r4[i];
            float d0 = dinv[r.x >> S_LOG], d1 = dinv[r.y >> S_LOG];
            float d2 = dinv[r.z >> S_LOG], d3 = dinv[r.w >> S_LOG];
            atomicAdd(&sd[r.x & (S - 1)], d0);
            atomicAdd(&sd[r.y & (S - 1)], d1);
            atomicAdd(&sd[r.z & (S - 1)], d2);
            atomicAdd(&sd[r.w & (S - 1)], d3);
        }
        for (int i = (m4 << 2) + t; i < ms; i += FT) {
            unsigned r = rec_s[lo + i];
            atomicAdd(&sd[r & (S - 1)], dinv[r >> S_LOG]);
        }
    }
    __syncthreads();
    // matvec + relu + weighted reduce; wave w: nodes w, w+8, ...; lane = channel
    int c = t & 63, w = t >> 6;
    float w0 = W1[c], w1 = W1[64 + c], w2 = W1[128 + c], w3 = W1[192 + c];
    float bb = b1[c];
    int nb0 = b << S_LOG;
    float facc = 0.0f;
    for (int k = w; k < S; k += 8) {
        int nd = nb0 + k;
        if (nd >= n) break;
        float di = dinv[nd];
        float4 yi = y[nd];
        // h_pre = di*(sum_in y + y_i)   (p1 + d2*x with y = di*x)
        float h0 = di * (a0[k] + yi.x);
        float h1 = di * (a1[k] + yi.y);
        float h2 = di * (a2[k] + yi.z);
        float h3 = di * (a3[k] + yi.w);
        float h = fmaf(h0, w0, fmaf(h1, w1, fmaf(h2, w2, fmaf(h3, w3, bb))));
        h = fmaxf(h, 0.0f);                 // relu(layer-1 output)
        float wi = di * (sd[k] + di);       // node weight (incl. self loop)
        facc = fmaf(wi, h, facc);
    }
    red[t] = facc;
    __syncthreads();
    if (t < 64) {
        float s = red[t];
        #pragma unroll
        for (int o = 1; o < 8; ++o) s += red[t + 64 * o];
        gAtomAdd(&g[t], s);
    }
}

// out[j] = b2[j] + (g @ W2)[j] / n
__global__ void k_final(const float* __restrict__ g, const float* __restrict__ W2,
                        const float* __restrict__ b2, float* __restrict__ out, float inv_n) {
    int j = threadIdx.x;
    if (j < 32) {
        float a = 0.0f;
        #pragma unroll
        for (int c = 0; c < 64; ++c) a = fmaf(g[c], W2[c * 32 + j], a);
        out[j] = fmaf(a, inv_n, b2[j]);
    }
}

extern "C" void kernel_launch(void* const* d_in, const int* in_sizes, int n_in,
                              void* d_out, int out_size, void* d_ws, size_t ws_size,
                              hipStream_t stream) {
    const float* x  = (const float*)d_in[0];
    const int*   ei = (const int*)d_in[1];
    const float* W1 = (const float*)d_in[2];
    const float* b1 = (const float*)d_in[3];
    const float* W2 = (const float*)d_in[4];
    const float* b2 = (const float*)d_in[5];
    float* out = (float*)d_out;

    int n = in_sizes[0] / 4;      // 100000
    int E = in_sizes[1] / 2;      // 3200000 (multiple of 4)
    const int* src = ei;
    const int* dst = ei + E;
    int NB = (n + S - 1) >> S_LOG;    // 391 buckets

    // workspace (4-byte words), ~30 MB:
    // cur_d[512] | cur_s[512] | g[64] | pad->1600 | rec_d[NB*CAP] | rec_s[NB*CAP]
    // | y[4n] | dinv[n]
    char* ws = (char*)d_ws;
    int* cur_d = (int*)ws;
    int* cur_s = cur_d + 512;
    float* g   = (float*)(cur_s + 512);
    size_t ctrl = 1600;
    unsigned* rec_d = (unsigned*)ws + ctrl;
    unsigned* rec_s = rec_d + (size_t)NB * CAP;
    float* yv   = (float*)(rec_s + (size_t)NB * CAP);   // 4n
    float* dinv = yv + 4 * (size_t)n;                   // n

    int NSB = (E + EPB - 1) / EPB;    // 391 scatter blocks

    k_init<<<1, 512, 0, stream>>>(cur_d, cur_s, g, NB);
    k_sctr2<<<NSB, ST, 0, stream>>>((const int4*)src, (const int4*)dst, E,
                                    cur_d, cur_s, rec_d, rec_s, NB);
    k_dy<<<NB, DT, 0, stream>>>(rec_d, cur_d, (const float4*)x, dinv,
                                (float4*)yv, n);
    k_acc2<<<NB, FT, 0, stream>>>(rec_d, rec_s, cur_d, cur_s,
                                  (const float4*)yv, dinv, W1, b1, g, n);
    k_final<<<1, 64, 0, stream>>>(g, W2, b2, out, 1.0f / (float)n);
}

// Round 13
// 156.851 us; speedup vs baseline: 1.4296x; 1.4296x over previous
//
#include <hip/hip_runtime.h>

#define ST 512           // threads, scatter kernel
#define EPB 8192         // edges per scatter block
#define CT 1024          // threads, csr+y kernel
#define FT 1024          // threads, fused p1+sumd+node kernel
#define S_LOG 8
#define S 256            // nodes per bucket
#define CAP 8912         // records per bucket (mean 8192 + 8 sigma)
#define MAXB 512         // bucket-array bound == ST (one entry per thread!)

__device__ __forceinline__ void gAtomAdd(float* p, float v) {
    unsafeAtomicAdd(p, v);  // hardware global_atomic_add_f32
}

// Init bucket cursors to fixed bases + zero g.
__global__ void k_init(int* __restrict__ cur_d, int* __restrict__ cur_s,
                       float* __restrict__ g, int nb) {
    int t = threadIdx.x;
    if (t < nb) { cur_d[t] = t * CAP; cur_s[t] = t * CAP; }
    if (t < 64) g[t] = 0.0f;
}

// Fused double bucket-scatter, rank-first (1 LDS atomic per record per phase).
// rec[pos] = (pay << 8) | (key & 255), grouped by key>>8 at fixed bucket bases.
// MAXB == ST: every bucket-array op is exactly one entry per thread. (R10-proven)
__global__ void __launch_bounds__(ST) k_sctr2(
        const int4* __restrict__ src4, const int4* __restrict__ dst4, int E,
        int* __restrict__ cur_d, int* __restrict__ cur_s,
        unsigned* __restrict__ rec_d, unsigned* __restrict__ rec_s, int nb) {
    __shared__ unsigned lrec[EPB];          // 32 KB
    __shared__ unsigned short lbkt[EPB];    // 16 KB
    __shared__ int cnt[MAXB];
    __shared__ int lst[MAXB];
    __shared__ int gb[MAXB];
    int t = threadIdx.x;
    int E4 = E >> 2;
    int b4 = blockIdx.x * (EPB / 4);
    int m = min(EPB, E - blockIdx.x * EPB);

    int4 dk[4], sk[4];
    bool v[4];
    #pragma unroll
    for (int k = 0; k < 4; ++k) {
        int idx = b4 + k * ST + t;
        v[k] = idx < E4;
        if (v[k]) { dk[k] = dst4[idx]; sk[k] = src4[idx]; }
    }

    for (int ph = 0; ph < 2; ++ph) {        // 0: by dst (pay src); 1: by src (pay dst)
        int* cursor = ph ? cur_s : cur_d;
        unsigned* rec = ph ? rec_s : rec_d;
        cnt[t] = 0;
        __syncthreads();
        int rk[16];
        #pragma unroll
        for (int k = 0; k < 4; ++k) {
            if (v[k]) {
                int4 K = ph ? sk[k] : dk[k];
                rk[4 * k + 0] = atomicAdd(&cnt[K.x >> S_LOG], 1);
                rk[4 * k + 1] = atomicAdd(&cnt[K.y >> S_LOG], 1);
                rk[4 * k + 2] = atomicAdd(&cnt[K.z >> S_LOG], 1);
                rk[4 * k + 3] = atomicAdd(&cnt[K.w >> S_LOG], 1);
            }
        }
        __syncthreads();
        int c = cnt[t];
        for (int o = 1; o < MAXB; o <<= 1) {
            int u = (t >= o) ? cnt[t - o] : 0;
            __syncthreads();
            cnt[t] += u;
            __syncthreads();
        }
        lst[t] = cnt[t] - c;
        gb[t] = (c > 0) ? atomicAdd(&cursor[t], c) : 0;
        __syncthreads();
        #pragma unroll
        for (int k = 0; k < 4; ++k) {
            if (v[k]) {
                int4 K = ph ? sk[k] : dk[k];
                int4 P = ph ? dk[k] : sk[k];
                int bb, p;
                bb = K.x >> S_LOG; p = lst[bb] + rk[4 * k + 0];
                lrec[p] = ((unsigned)P.x << S_LOG) | (unsigned)(K.x & (S - 1));
                lbkt[p] = (unsigned short)bb;
                bb = K.y >> S_LOG; p = lst[bb] + rk[4 * k + 1];
                lrec[p] = ((unsigned)P.y << S_LOG) | (unsigned)(K.y & (S - 1));
                lbkt[p] = (unsigned short)bb;
                bb = K.z >> S_LOG; p = lst[bb] + rk[4 * k + 2];
                lrec[p] = ((unsigned)P.z << S_LOG) | (unsigned)(K.z & (S - 1));
                lbkt[p] = (unsigned short)bb;
                bb = K.w >> S_LOG; p = lst[bb] + rk[4 * k + 3];
                lrec[p] = ((unsigned)P.w << S_LOG) | (unsigned)(K.w & (S - 1));
                lbkt[p] = (unsigned short)bb;
            }
        }
        __syncthreads();
        for (int i = t; i < m; i += ST) {   // coalesced per-bucket-run flush
            int bb = lbkt[i];
            rec[gb[bb] + (i - lst[bb])] = lrec[i];
        }
        __syncthreads();
    }
}

// Per dst-bucket, rank-first: node histogram -> dinv + y = dinv*x + CSR bounds,
// sorted writeback of rec_d (src ids, grouped by dst node).
__global__ void __launch_bounds__(CT) k_csry(
        unsigned* __restrict__ rec, const int* __restrict__ cur_d,
        const float4* __restrict__ x, float* __restrict__ dinv,
        float4* __restrict__ y, int* __restrict__ nst_g, int* __restrict__ nend_g,
        int n) {
    __shared__ unsigned lrec[CAP];
    __shared__ int cnt[S];
    __shared__ int nst[S];
    int b = blockIdx.x, t = threadIdx.x;
    int lo = b * CAP;
    int m = cur_d[b] - lo;
    if (t < S) cnt[t] = 0;
    __syncthreads();
    unsigned rv[9]; int rr[9];
    #pragma unroll
    for (int k = 0; k < 9; ++k) {
        int i = t + k * CT;
        if (i < m) {
            unsigned r = rec[lo + i];
            rv[k] = r;
            rr[k] = atomicAdd(&cnt[r & (S - 1)], 1);
        }
    }
    __syncthreads();
    int deg = (t < S) ? cnt[t] : 0;
    int nd = (b << S_LOG) + t;
    if (t < S && nd < n) {
        float dv = rsqrtf((float)deg + 1.0f);
        dinv[nd] = dv;
        float4 xi = x[nd];
        y[nd] = make_float4(dv * xi.x, dv * xi.y, dv * xi.z, dv * xi.w);
    }
    // inclusive scan of cnt[256]
    for (int o = 1; o < S; o <<= 1) {
        int u = (t < S && t >= o) ? cnt[t - o] : 0;
        __syncthreads();
        if (t < S) cnt[t] += u;
        __syncthreads();
    }
    if (t < S) {
        int st = cnt[t] - deg;
        nst[t] = st;
        if (nd < n) { nst_g[nd] = lo + st; nend_g[nd] = lo + st + deg; }
    }
    __syncthreads();
    #pragma unroll
    for (int k = 0; k < 9; ++k) {
        int i = t + k * CT;
        if (i < m) lrec[nst[rv[k] & (S - 1)] + rr[k]] = rv[k] >> S_LOG;
    }
    __syncthreads();
    for (int i = t; i < m; i += CT) rec[lo + i] = lrec[i];   // coalesced writeback
}

// Per bucket, fused: (b) sumd from rec_s via LDS atomics; (a) p1 accumulate from
// node-sorted rec_d into LDS (quad/node, 8-wide batched y-gathers); (c) layer-1
// matvec + relu + weighted g-reduce. p1 never touches global memory.
__global__ void __launch_bounds__(FT) k_fuse(
        const unsigned* __restrict__ rec_d, const unsigned* __restrict__ rec_s,
        const int* __restrict__ cur_s, const int* __restrict__ nst_g,
        const int* __restrict__ nend_g, const float4* __restrict__ y,
        const float* __restrict__ dinv,
        const float* __restrict__ W1, const float* __restrict__ b1,
        float* __restrict__ g, int n) {
    __shared__ float a[S];
    __shared__ float4 lp1[S];
    __shared__ float red[FT];
    int b = blockIdx.x, t = threadIdx.x;
    if (t < S) a[t] = 0.0f;
    __syncthreads();
    // (b) sumd[loc] += dinv[dst] over src-grouped records (4-wide batched gathers)
    int lo = b * CAP;
    int m = cur_s[b] - lo;
    int m4 = m >> 2;
    const uint4* rec4 = (const uint4*)(rec_s + lo);
    for (int i = t; i < m4; i += FT) {
        uint4 r = rec4[i];
        float d0 = dinv[r.x >> S_LOG], d1 = dinv[r.y >> S_LOG];
        float d2 = dinv[r.z >> S_LOG], d3 = dinv[r.w >> S_LOG];
        atomicAdd(&a[r.x & (S - 1)], d0);
        atomicAdd(&a[r.y & (S - 1)], d1);
        atomicAdd(&a[r.z & (S - 1)], d2);
        atomicAdd(&a[r.w & (S - 1)], d3);
    }
    for (int i = (m4 << 2) + t; i < m; i += FT) {
        unsigned r = rec_s[lo + i];
        atomicAdd(&a[r & (S - 1)], dinv[r >> S_LOG]);
    }
    // (a) p1 for this bucket's nodes: 4 threads/node, 8-wide batched y-gathers
    int node = t >> 2, q = t & 3;
    int nd = (b << S_LOG) + node;
    if (nd < n) {
        int j1 = nend_g[nd];
        int j = nst_g[nd] + q;
        float a0 = 0.0f, a1 = 0.0f, a2 = 0.0f, a3 = 0.0f;
        for (; j + 28 < j1; j += 32) {   // 8 records per lane per batch
            int s0 = rec_d[j],      s1 = rec_d[j + 4],  s2 = rec_d[j + 8],  s3 = rec_d[j + 12];
            int s4 = rec_d[j + 16], s5 = rec_d[j + 20], s6 = rec_d[j + 24], s7 = rec_d[j + 28];
            float4 y0 = y[s0], y1 = y[s1], y2 = y[s2], y3 = y[s3];
            float4 y4 = y[s4], y5 = y[s5], y6 = y[s6], y7 = y[s7];
            a0 += (y0.x + y1.x) + (y2.x + y3.x) + (y4.x + y5.x) + (y6.x + y7.x);
            a1 += (y0.y + y1.y) + (y2.y + y3.y) + (y4.y + y5.y) + (y6.y + y7.y);
            a2 += (y0.z + y1.z) + (y2.z + y3.z) + (y4.z + y5.z) + (y6.z + y7.z);
            a3 += (y0.w + y1.w) + (y2.w + y3.w) + (y4.w + y5.w) + (y6.w + y7.w);
        }
        for (; j + 12 < j1; j += 16) {   // 4-wide tail batch
            int s0 = rec_d[j], s1 = rec_d[j + 4], s2 = rec_d[j + 8], s3 = rec_d[j + 12];
            float4 y0 = y[s0], y1 = y[s1], y2 = y[s2], y3 = y[s3];
            a0 += (y0.x + y1.x) + (y2.x + y3.x);
            a1 += (y0.y + y1.y) + (y2.y + y3.y);
            a2 += (y0.z + y1.z) + (y2.z + y3.z);
            a3 += (y0.w + y1.w) + (y2.w + y3.w);
        }
        for (; j < j1; j += 4) {
            float4 ys = y[rec_d[j]];
            a0 += ys.x; a1 += ys.y; a2 += ys.z; a3 += ys.w;
        }
        a0 += __shfl_down(a0, 2); a1 += __shfl_down(a1, 2);
        a2 += __shfl_down(a2, 2); a3 += __shfl_down(a3, 2);
        a0 += __shfl_down(a0, 1); a1 += __shfl_down(a1, 1);
        a2 += __shfl_down(a2, 1); a3 += __shfl_down(a3, 1);
        if (q == 0) {
            float di = dinv[nd];
            lp1[node] = make_float4(di * a0, di * a1, di * a2, di * a3);
        }
    }
    __syncthreads();
    // (c) matvec + relu + weighted reduce; wave w: nodes w, w+16, ...; lane = channel
    int c = t & 63, w = t >> 6;
    float w0 = W1[c], w1 = W1[64 + c], w2 = W1[128 + c], w3 = W1[192 + c];
    float bb = b1[c];
    int nb0 = b << S_LOG;
    float facc = 0.0f;
    for (int k = w; k < S; k += 16) {
        int ndk = nb0 + k;
        if (ndk >= n) break;
        float di = dinv[ndk];
        float4 p = lp1[k];
        float4 yi = y[ndk];                 // d2*x == di*y
        float h0 = fmaf(di, yi.x, p.x);
        float h1 = fmaf(di, yi.y, p.y);
        float h2 = fmaf(di, yi.z, p.z);
        float h3 = fmaf(di, yi.w, p.w);
        float h = fmaf(h0, w0, fmaf(h1, w1, fmaf(h2, w2, fmaf(h3, w3, bb))));
        h = fmaxf(h, 0.0f);                 // relu(layer-1 output)
        float wi = fmaf(di, a[k], di * di); // node weight (incl. self loop)
        facc = fmaf(wi, h, facc);
    }
    red[t] = facc;
    __syncthreads();
    if (t < 64) {
        float s = red[t];
        #pragma unroll
        for (int o = 1; o < 16; ++o) s += red[t + 64 * o];
        gAtomAdd(&g[t], s);
    }
}

// out[j] = b2[j] + (g @ W2)[j] / n
__global__ void k_final(const float* __restrict__ g, const float* __restrict__ W2,
                        const float* __restrict__ b2, float* __restrict__ out, float inv_n) {
    int j = threadIdx.x;
    if (j < 32) {
        float a = 0.0f;
        #pragma unroll
        for (int c = 0; c < 64; ++c) a = fmaf(g[c], W2[c * 32 + j], a);
        out[j] = fmaf(a, inv_n, b2[j]);
    }
}

extern "C" void kernel_launch(void* const* d_in, const int* in_sizes, int n_in,
                              void* d_out, int out_size, void* d_ws, size_t ws_size,
                              hipStream_t stream) {
    const float* x  = (const float*)d_in[0];
    const int*   ei = (const int*)d_in[1];
    const float* W1 = (const float*)d_in[2];
    const float* b1 = (const float*)d_in[3];
    const float* W2 = (const float*)d_in[4];
    const float* b2 = (const float*)d_in[5];
    float* out = (float*)d_out;

    int n = in_sizes[0] / 4;      // 100000
    int E = in_sizes[1] / 2;      // 3200000 (multiple of 4)
    const int* src = ei;
    const int* dst = ei + E;
    int NB = (n + S - 1) >> S_LOG;    // 391 buckets

    // workspace (4-byte words), ~33 MB:
    // cur_d[512] | cur_s[512] | g[64] | pad->1600 | rec_d[NB*CAP] | rec_s[NB*CAP]
    // | y[4n] | dinv[n] | nst_g[n] | nend_g[n]
    char* ws = (char*)d_ws;
    int* cur_d = (int*)ws;
    int* cur_s = cur_d + 512;
    float* g   = (float*)(cur_s + 512);
    size_t ctrl = 1600;
    unsigned* rec_d = (unsigned*)ws + ctrl;
    unsigned* rec_s = rec_d + (size_t)NB * CAP;
    float* y    = (float*)(rec_s + (size_t)NB * CAP);   // 4n
    float* dinv = y + 4 * (size_t)n;                    // n
    int* nst_g  = (int*)(dinv + (size_t)n);             // n
    int* nend_g = nst_g + (size_t)n;                    // n

    int NSB = (E + EPB - 1) / EPB;    // 391 scatter blocks

    k_init<<<1, 512, 0, stream>>>(cur_d, cur_s, g, NB);
    k_sctr2<<<NSB, ST, 0, stream>>>((const int4*)src, (const int4*)dst, E,
                                    cur_d, cur_s, rec_d, rec_s, NB);
    k_csry<<<NB, CT, 0, stream>>>(rec_d, cur_d, (const float4*)x, dinv,
                                  (float4*)y, nst_g, nend_g, n);
    k_fuse<<<NB, FT, 0, stream>>>(rec_d, rec_s, cur_s, nst_g, nend_g,
                                  (const float4*)y, dinv, W1, b1, g, n);
    k_final<<<1, 64, 0, stream>>>(g, W2, b2, out, 1.0f / (float)n);
}

// Round 14
// 155.106 us; speedup vs baseline: 1.4457x; 1.0112x over previous
//
#include <hip/hip_runtime.h>

#define ST 512           // threads, scatter kernel
#define EPB 8192         // edges per scatter block
#define DT 512           // threads, degree/y kernel
#define MT 1024          // threads, merged sort+accumulate kernel
#define S_LOG 8
#define S 256            // nodes per bucket
#define CAP 8912         // records per bucket (mean 8192 + 8 sigma)
#define MAXB 512         // bucket-array bound == ST (one entry per thread!)

__device__ __forceinline__ void gAtomAdd(float* p, float v) {
    unsafeAtomicAdd(p, v);  // hardware global_atomic_add_f32
}

// Init bucket cursors to fixed bases + zero g.
__global__ void k_init(int* __restrict__ cur_d, int* __restrict__ cur_s,
                       float* __restrict__ g, int nb) {
    int t = threadIdx.x;
    if (t < nb) { cur_d[t] = t * CAP; cur_s[t] = t * CAP; }
    if (t < 64) g[t] = 0.0f;
}

// Single-phase bucket-scatter, rank-first. Phase selected by blockIdx:
// [0,NSB) sorts by dst (payload src) -> rec_d; [NSB,2*NSB) by src -> rec_s.
// rec[pos] = (pay << 8) | (key & 255), grouped by key>>8 at fixed bucket bases.
__global__ void __launch_bounds__(ST) k_sctr1(
        const int4* __restrict__ src4, const int4* __restrict__ dst4, int E, int NSB,
        int* __restrict__ cur_d, int* __restrict__ cur_s,
        unsigned* __restrict__ rec_d, unsigned* __restrict__ rec_s, int nb) {
    __shared__ unsigned lrec[EPB];          // 32 KB
    __shared__ unsigned short lbkt[EPB];    // 16 KB
    __shared__ int cnt[MAXB];
    __shared__ int lst[MAXB];
    __shared__ int gb[MAXB];
    int t = threadIdx.x;
    int ph = blockIdx.x >= NSB;
    int bid = ph ? blockIdx.x - NSB : blockIdx.x;
    const int4* key4 = ph ? src4 : dst4;
    const int4* pay4 = ph ? dst4 : src4;
    int* cursor = ph ? cur_s : cur_d;
    unsigned* rec = ph ? rec_s : rec_d;
    int E4 = E >> 2;
    int b4 = bid * (EPB / 4);
    int m = min(EPB, E - bid * EPB);

    cnt[t] = 0;
    __syncthreads();
    int4 K[4], P[4];
    bool v[4];
    int rk[16];
    #pragma unroll
    for (int k = 0; k < 4; ++k) {
        int idx = b4 + k * ST + t;
        v[k] = idx < E4;
        if (v[k]) { K[k] = key4[idx]; P[k] = pay4[idx]; }
    }
    #pragma unroll
    for (int k = 0; k < 4; ++k) {
        if (v[k]) {
            rk[4 * k + 0] = atomicAdd(&cnt[K[k].x >> S_LOG], 1);
            rk[4 * k + 1] = atomicAdd(&cnt[K[k].y >> S_LOG], 1);
            rk[4 * k + 2] = atomicAdd(&cnt[K[k].z >> S_LOG], 1);
            rk[4 * k + 3] = atomicAdd(&cnt[K[k].w >> S_LOG], 1);
        }
    }
    __syncthreads();
    int c = cnt[t];
    for (int o = 1; o < MAXB; o <<= 1) {    // inclusive Hillis-Steele, 1 entry/thread
        int u = (t >= o) ? cnt[t - o] : 0;
        __syncthreads();
        cnt[t] += u;
        __syncthreads();
    }
    lst[t] = cnt[t] - c;
    gb[t] = (c > 0) ? atomicAdd(&cursor[t], c) : 0;
    __syncthreads();
    #pragma unroll
    for (int k = 0; k < 4; ++k) {
        if (v[k]) {
            int bb, p;
            bb = K[k].x >> S_LOG; p = lst[bb] + rk[4 * k + 0];
            lrec[p] = ((unsigned)P[k].x << S_LOG) | (unsigned)(K[k].x & (S - 1));
            lbkt[p] = (unsigned short)bb;
            bb = K[k].y >> S_LOG; p = lst[bb] + rk[4 * k + 1];
            lrec[p] = ((unsigned)P[k].y << S_LOG) | (unsigned)(K[k].y & (S - 1));
            lbkt[p] = (unsigned short)bb;
            bb = K[k].z >> S_LOG; p = lst[bb] + rk[4 * k + 2];
            lrec[p] = ((unsigned)P[k].z << S_LOG) | (unsigned)(K[k].z & (S - 1));
            lbkt[p] = (unsigned short)bb;
            bb = K[k].w >> S_LOG; p = lst[bb] + rk[4 * k + 3];
            lrec[p] = ((unsigned)P[k].w << S_LOG) | (unsigned)(K[k].w & (S - 1));
            lbkt[p] = (unsigned short)bb;
        }
    }
    __syncthreads();
    for (int i = t; i < m; i += ST) {       // coalesced per-bucket-run flush
        int bb = lbkt[i];
        rec[gb[bb] + (i - lst[bb])] = lrec[i];
    }
}

// Per dst-bucket: in-degree histogram -> dinv + y = dinv*x. No sort, no writeback.
__global__ void __launch_bounds__(DT) k_dy(
        const unsigned* __restrict__ rec_d, const int* __restrict__ cur_d,
        const float4* __restrict__ x, float* __restrict__ dinv,
        float4* __restrict__ y, int n) {
    __shared__ int cnt[S];
    int b = blockIdx.x, t = threadIdx.x;
    int lo = b * CAP;
    int md = cur_d[b] - lo;
    if (t < S) cnt[t] = 0;
    __syncthreads();
    int m4 = md >> 2;
    const uint4* r4 = (const uint4*)(rec_d + lo);
    for (int i = t; i < m4; i += DT) {
        uint4 r = r4[i];
        atomicAdd(&cnt[r.x & (S - 1)], 1);
        atomicAdd(&cnt[r.y & (S - 1)], 1);
        atomicAdd(&cnt[r.z & (S - 1)], 1);
        atomicAdd(&cnt[r.w & (S - 1)], 1);
    }
    for (int i = (m4 << 2) + t; i < md; i += DT)
        atomicAdd(&cnt[rec_d[lo + i] & (S - 1)], 1);
    __syncthreads();
    if (t < S) {
        int nd = (b << S_LOG) + t;
        if (nd < n) {
            float dv = rsqrtf((float)cnt[t] + 1.0f);
            dinv[nd] = dv;
            float4 xi = x[nd];
            y[nd] = make_float4(dv * xi.x, dv * xi.y, dv * xi.z, dv * xi.w);
        }
    }
}

// Per bucket, merged: rank-sort rec_d into LDS (node-grouped, no writeback),
// sumd from rec_s (overlapped before the sort barrier), p1 register-accumulate
// from LDS-resident sorted list, matvec + relu + weighted g-reduce.
__global__ void __launch_bounds__(MT) k_mrg(
        const unsigned* __restrict__ rec_d, const unsigned* __restrict__ rec_s,
        const int* __restrict__ cur_d, const int* __restrict__ cur_s,
        const float4* __restrict__ y, const float* __restrict__ dinv,
        const float* __restrict__ W1, const float* __restrict__ b1,
        float* __restrict__ g, int n) {
    __shared__ unsigned lrec[CAP];          // node-sorted src ids (35.6 KB)
    __shared__ int cnt[S], nst[S];
    __shared__ float sd[S];
    __shared__ float4 lp1[S];
    __shared__ float red[MT];
    int b = blockIdx.x, t = threadIdx.x;
    int lo = b * CAP;
    int md = cur_d[b] - lo;
    if (t < S) { cnt[t] = 0; sd[t] = 0.0f; }
    __syncthreads();
    // rank-first staging of rec_d
    unsigned rv[9]; int rr[9];
    #pragma unroll
    for (int k = 0; k < 9; ++k) {
        int i = t + k * MT;
        if (i < md) {
            unsigned r = rec_d[lo + i];
            rv[k] = r;
            rr[k] = atomicAdd(&cnt[r & (S - 1)], 1);
        }
    }
    __syncthreads();
    int deg = (t < S) ? cnt[t] : 0;
    for (int o = 1; o < S; o <<= 1) {       // inclusive scan of cnt[256]
        int u = (t < S && t >= o) ? cnt[t - o] : 0;
        __syncthreads();
        if (t < S) cnt[t] += u;
        __syncthreads();
    }
    if (t < S) nst[t] = cnt[t] - deg;
    __syncthreads();
    #pragma unroll
    for (int k = 0; k < 9; ++k) {
        int i = t + k * MT;
        if (i < md) lrec[nst[rv[k] & (S - 1)] + rr[k]] = rv[k] >> S_LOG;
    }
    // sumd from rec_s — global reads, independent of lrec: overlaps the sort tail
    {
        int ms = cur_s[b] - lo;
        int m4 = ms >> 2;
        const uint4* r4 = (const uint4*)(rec_s + lo);
        for (int i = t; i < m4; i += MT) {
            uint4 r = r4[i];
            float d0 = dinv[r.x >> S_LOG], d1 = dinv[r.y >> S_LOG];
            float d2 = dinv[r.z >> S_LOG], d3 = dinv[r.w >> S_LOG];
            atomicAdd(&sd[r.x & (S - 1)], d0);
            atomicAdd(&sd[r.y & (S - 1)], d1);
            atomicAdd(&sd[r.z & (S - 1)], d2);
            atomicAdd(&sd[r.w & (S - 1)], d3);
        }
        for (int i = (m4 << 2) + t; i < ms; i += MT) {
            unsigned r = rec_s[lo + i];
            atomicAdd(&sd[r & (S - 1)], dinv[r >> S_LOG]);
        }
    }
    __syncthreads();
    // p1: 4 threads/node, indices from LDS, 8-wide batched y-gathers
    int node = t >> 2, q = t & 3;
    int nd = (b << S_LOG) + node;
    if (nd < n) {
        int j = nst[node] + q;
        int j1 = cnt[node];                 // inclusive scan == segment end
        float a0 = 0.0f, a1 = 0.0f, a2 = 0.0f, a3 = 0.0f;
        for (; j + 28 < j1; j += 32) {
            int s0 = lrec[j],      s1 = lrec[j + 4],  s2 = lrec[j + 8],  s3 = lrec[j + 12];
            int s4 = lrec[j + 16], s5 = lrec[j + 20], s6 = lrec[j + 24], s7 = lrec[j + 28];
            float4 y0 = y[s0], y1 = y[s1], y2 = y[s2], y3 = y[s3];
            float4 y4 = y[s4], y5 = y[s5], y6 = y[s6], y7 = y[s7];
            a0 += (y0.x + y1.x) + (y2.x + y3.x) + (y4.x + y5.x) + (y6.x + y7.x);
            a1 += (y0.y + y1.y) + (y2.y + y3.y) + (y4.y + y5.y) + (y6.y + y7.y);
            a2 += (y0.z + y1.z) + (y2.z + y3.z) + (y4.z + y5.z) + (y6.z + y7.z);
            a3 += (y0.w + y1.w) + (y2.w + y3.w) + (y4.w + y5.w) + (y6.w + y7.w);
        }
        for (; j + 12 < j1; j += 16) {
            int s0 = lrec[j], s1 = lrec[j + 4], s2 = lrec[j + 8], s3 = lrec[j + 12];
            float4 y0 = y[s0], y1 = y[s1], y2 = y[s2], y3 = y[s3];
            a0 += (y0.x + y1.x) + (y2.x + y3.x);
            a1 += (y0.y + y1.y) + (y2.y + y3.y);
            a2 += (y0.z + y1.z) + (y2.z + y3.z);
            a3 += (y0.w + y1.w) + (y2.w + y3.w);
        }
        for (; j < j1; j += 4) {
            float4 ys = y[lrec[j]];
            a0 += ys.x; a1 += ys.y; a2 += ys.z; a3 += ys.w;
        }
        a0 += __shfl_down(a0, 2); a1 += __shfl_down(a1, 2);
        a2 += __shfl_down(a2, 2); a3 += __shfl_down(a3, 2);
        a0 += __shfl_down(a0, 1); a1 += __shfl_down(a1, 1);
        a2 += __shfl_down(a2, 1); a3 += __shfl_down(a3, 1);
        if (q == 0) {
            float di = dinv[nd];
            lp1[node] = make_float4(di * a0, di * a1, di * a2, di * a3);
        }
    }
    __syncthreads();
    // matvec + relu + weighted reduce; wave w: nodes w, w+16, ...; lane = channel
    int c = t & 63, w = t >> 6;
    float w0 = W1[c], w1 = W1[64 + c], w2 = W1[128 + c], w3 = W1[192 + c];
    float bb = b1[c];
    int nb0 = b << S_LOG;
    float facc = 0.0f;
    for (int k = w; k < S; k += 16) {
        int ndk = nb0 + k;
        if (ndk >= n) break;
        float di = dinv[ndk];
        float4 p = lp1[k];
        float4 yi = y[ndk];                 // d2*x == di*y
        float h0 = fmaf(di, yi.x, p.x);
        float h1 = fmaf(di, yi.y, p.y);
        float h2 = fmaf(di, yi.z, p.z);
        float h3 = fmaf(di, yi.w, p.w);
        float h = fmaf(h0, w0, fmaf(h1, w1, fmaf(h2, w2, fmaf(h3, w3, bb))));
        h = fmaxf(h, 0.0f);                 // relu(layer-1 output)
        float wi = fmaf(di, sd[k], di * di);// node weight (incl. self loop)
        facc = fmaf(wi, h, facc);
    }
    red[t] = facc;
    __syncthreads();
    if (t < 64) {
        float s = red[t];
        #pragma unroll
        for (int o = 1; o < 16; ++o) s += red[t + 64 * o];
        gAtomAdd(&g[t], s);
    }
}

// out[j] = b2[j] + (g @ W2)[j] / n
__global__ void k_final(const float* __restrict__ g, const float* __restrict__ W2,
                        const float* __restrict__ b2, float* __restrict__ out, float inv_n) {
    int j = threadIdx.x;
    if (j < 32) {
        float a = 0.0f;
        #pragma unroll
        for (int c = 0; c < 64; ++c) a = fmaf(g[c], W2[c * 32 + j], a);
        out[j] = fmaf(a, inv_n, b2[j]);
    }
}

extern "C" void kernel_launch(void* const* d_in, const int* in_sizes, int n_in,
                              void* d_out, int out_size, void* d_ws, size_t ws_size,
                              hipStream_t stream) {
    const float* x  = (const float*)d_in[0];
    const int*   ei = (const int*)d_in[1];
    const float* W1 = (const float*)d_in[2];
    const float* b1 = (const float*)d_in[3];
    const float* W2 = (const float*)d_in[4];
    const float* b2 = (const float*)d_in[5];
    float* out = (float*)d_out;

    int n = in_sizes[0] / 4;      // 100000
    int E = in_sizes[1] / 2;      // 3200000 (multiple of 4)
    const int* src = ei;
    const int* dst = ei + E;
    int NB = (n + S - 1) >> S_LOG;    // 391 buckets

    // workspace (4-byte words), ~31 MB:
    // cur_d[512] | cur_s[512] | g[64] | pad->1600 | rec_d[NB*CAP] | rec_s[NB*CAP]
    // | y[4n] | dinv[n]
    char* ws = (char*)d_ws;
    int* cur_d = (int*)ws;
    int* cur_s = cur_d + 512;
    float* g   = (float*)(cur_s + 512);
    size_t ctrl = 1600;
    unsigned* rec_d = (unsigned*)ws + ctrl;
    unsigned* rec_s = rec_d + (size_t)NB * CAP;
    float* yv   = (float*)(rec_s + (size_t)NB * CAP);   // 4n
    float* dinv = yv + 4 * (size_t)n;                   // n

    int NSB = (E + EPB - 1) / EPB;    // 391 edge blocks per phase

    k_init<<<1, 512, 0, stream>>>(cur_d, cur_s, g, NB);
    k_sctr1<<<2 * NSB, ST, 0, stream>>>((const int4*)src, (const int4*)dst, E, NSB,
                                        cur_d, cur_s, rec_d, rec_s, NB);
    k_dy<<<NB, DT, 0, stream>>>(rec_d, cur_d, (const float4*)x, dinv,
                                (float4*)yv, n);
    k_mrg<<<NB, MT, 0, stream>>>(rec_d, rec_s, cur_d, cur_s,
                                 (const float4*)yv, dinv, W1, b1, g, n);
    k_final<<<1, 64, 0, stream>>>(g, W2, b2, out, 1.0f / (float)n);
}